// Round 3
// baseline (2283.426 us; speedup 1.0000x reference)
//
#include <hip/hip_runtime.h>

// Shapes
constexpr int Bb = 16, Nn = 512, Cc = 64, Tt = 12, Hh = 64;
constexpr int NCT = Nn * Cc * Tt;     // 393216
constexpr int CT  = Cc * Tt;          // 768

// ---------------------------------------------------------------------------
// K0: transpose res_w [H][C] -> resT [C][H]
__global__ void k0_rest(const float* __restrict__ rw, float* __restrict__ resT) {
    int i = blockIdx.x * 256 + threadIdx.x;        // i = h*64 + c
    if (i < Hh * Cc) {
        int h = i >> 6, c = i & 63;
        resT[c * 64 + h] = rw[i];
    }
}

// ---------------------------------------------------------------------------
// K1a: tmp1[b][c*12+t] = sum_n x[b,n,c,t] * U1[n]   (partial over n-chunk, atomic)
__global__ void k1a_tmp1(const float* __restrict__ x, const float* __restrict__ U1,
                         float* __restrict__ tmp1) {
    int blk = blockIdx.x;                 // 16 * 3 * 4 = 192
    int b = blk / 12; int r = blk % 12;
    int ctb = r >> 2; int nch = r & 3;
    int ct = ctb * 256 + threadIdx.x;
    const float* xb = x + (size_t)b * NCT;
    float acc = 0.f;
    int n0 = nch * 128;
    for (int n = n0; n < n0 + 128; ++n)
        acc += xb[n * CT + ct] * U1[n];
    atomicAdd(&tmp1[b * CT + ct], acc);
}

// K1b: rhs[b][n][t] = sum_c U3[c] * x[b,n,c,t]
__global__ void k1b_rhs(const float* __restrict__ x, const float* __restrict__ U3,
                        float* __restrict__ rhs) {
    int idx = blockIdx.x * 256 + threadIdx.x;   // B*N*T = 98304
    int b = idx / (Nn * Tt);
    int r = idx % (Nn * Tt);
    int n = r / Tt; int t = r % Tt;
    const float* xr = x + (size_t)b * NCT + n * CT + t;
    float a = 0.f;
    for (int c = 0; c < Cc; ++c) a += xr[c * Tt] * U3[c];
    rhs[idx] = a;
}

// K1c: per-batch: lhs, product, E, softmax -> At[b][12][12]
__global__ void k1c_att(const float* __restrict__ tmp1, const float* __restrict__ rhs,
                        const float* __restrict__ U2, const float* __restrict__ be,
                        const float* __restrict__ Ve, float* __restrict__ At) {
    __shared__ float t1[CT];
    __shared__ float rh[Nn * Tt];
    __shared__ float lh[Tt * Nn];
    __shared__ float sp[144];
    __shared__ float Ee[144];
    int b = blockIdx.x, tid = threadIdx.x;
    for (int i = tid; i < CT; i += 256) t1[i] = tmp1[b * CT + i];
    for (int i = tid; i < Nn * Tt; i += 256) rh[i] = rhs[b * Nn * Tt + i];
    __syncthreads();
    for (int nn = tid; nn < Nn; nn += 256) {
        float l[Tt];
        #pragma unroll
        for (int t = 0; t < Tt; ++t) l[t] = 0.f;
        for (int c = 0; c < Cc; ++c) {
            float u2 = U2[c * Nn + nn];
            #pragma unroll
            for (int t = 0; t < Tt; ++t) l[t] += t1[c * Tt + t] * u2;
        }
        #pragma unroll
        for (int t = 0; t < Tt; ++t) lh[t * Nn + nn] = l[t];
    }
    __syncthreads();
    if (tid < 144) {
        int t = tid / 12, s2 = tid % 12;
        float a = 0.f;
        for (int nn = 0; nn < Nn; ++nn) a += lh[t * Nn + nn] * rh[nn * Tt + s2];
        a += be[tid];
        sp[tid] = 1.f / (1.f + __expf(-a));
    }
    __syncthreads();
    if (tid < 144) {
        int i = tid / 12, k = tid % 12;
        float a = 0.f;
        #pragma unroll
        for (int j = 0; j < 12; ++j) a += Ve[i * 12 + j] * sp[j * 12 + k];
        Ee[tid] = a;
    }
    __syncthreads();
    if (tid < 12) {
        int k = tid;
        float mx = -1e30f;
        #pragma unroll
        for (int i = 0; i < 12; ++i) mx = fmaxf(mx, Ee[i * 12 + k]);
        float su = 0.f; float ex[12];
        #pragma unroll
        for (int i = 0; i < 12; ++i) { ex[i] = __expf(Ee[i * 12 + k] - mx); su += ex[i]; }
        float inv = 1.f / su;
        #pragma unroll
        for (int i = 0; i < 12; ++i) At[b * 144 + i * 12 + k] = ex[i] * inv;
    }
}

// ---------------------------------------------------------------------------
// K2: xtT[b][t][c][n] = sum_tau x[b,n,c,tau] * At[b,tau,t]
__global__ void k2_xtt(const float* __restrict__ x, const float* __restrict__ At,
                       float* __restrict__ xtT) {
    int idx = blockIdx.x * 256 + threadIdx.x;  // B*C*N = 524288, n fastest
    int n = idx & 511; int c = (idx >> 9) & 63; int b = idx >> 15;
    const float* xr = x + (size_t)((b * Nn + n) * Cc + c) * Tt;
    float xv[Tt];
    {
        const float4* x4 = (const float4*)xr;
        float4 a0 = x4[0], a1 = x4[1], a2 = x4[2];
        xv[0]=a0.x; xv[1]=a0.y; xv[2]=a0.z; xv[3]=a0.w;
        xv[4]=a1.x; xv[5]=a1.y; xv[6]=a1.z; xv[7]=a1.w;
        xv[8]=a2.x; xv[9]=a2.y; xv[10]=a2.z; xv[11]=a2.w;
    }
    const float* Ab = At + b * 144;
    for (int t = 0; t < Tt; ++t) {
        float a = 0.f;
        #pragma unroll
        for (int u = 0; u < Tt; ++u) a += xv[u] * Ab[u * 12 + t];
        xtT[((size_t)(b * Tt + t) * Cc + c) * Nn + n] = a;
    }
}

// K2b: enhT[t][m][n] = adj[n][m] * sigmoid(masks[t][n][m])  (tiled transpose)
__global__ void k2b_enh(const float* __restrict__ adj, const float* __restrict__ masks,
                        float* __restrict__ enhT) {
    __shared__ float tile[32][33];
    int blk = blockIdx.x;              // 12 * 16 * 16 = 3072
    int t = blk >> 8; int r = blk & 255;
    int n0 = (r >> 4) * 32; int m0 = (r & 15) * 32;
    int tx = threadIdx.x & 31; int ty = threadIdx.x >> 5;   // ty 0..7
    #pragma unroll
    for (int i = 0; i < 4; ++i) {
        int nl = ty + 8 * i;
        float a  = adj[(n0 + nl) * Nn + m0 + tx];
        float mk = masks[t * Nn * Nn + (n0 + nl) * Nn + m0 + tx];
        tile[nl][tx] = a / (1.f + __expf(-mk));
    }
    __syncthreads();
    #pragma unroll
    for (int i = 0; i < 4; ++i) {
        int ml = ty + 8 * i;
        enhT[(size_t)(t * Nn + m0 + ml) * Nn + n0 + tx] = tile[tx][ml];
    }
}

// ---------------------------------------------------------------------------
// K3: per (b,t,n-quarter): scores+softmax+d, s, projections -> F[b][t][n][h]
__global__ __launch_bounds__(128, 2) void k3_gcn(
    const float* __restrict__ xtT, const float* __restrict__ enhT,
    const float* __restrict__ W0, const float* __restrict__ b0,
    const float* __restrict__ Ws, const float* __restrict__ bs,
    const float* __restrict__ Wd, const float* __restrict__ bd,
    float* __restrict__ F) {
    __shared__ float sm[128 * 65];
    int blk = blockIdx.x;              // 768 = B*T*4
    int nq = blk & 3; int t = (blk >> 2) % Tt; int b = blk / (Tt * 4);
    int n = nq * 128 + threadIdx.x;
    const float* xb = xtT + (size_t)(b * Tt + t) * Cc * Nn;  // [C][N]
    float row[64], accd[64], accs[64];
    #pragma unroll
    for (int c = 0; c < 64; ++c) row[c] = xb[c * Nn + n];
    #pragma unroll
    for (int c = 0; c < 64; ++c) { accd[c] = 0.f; accs[c] = 0.f; }
    float sumexp = 0.f;
    const float* ehT = enhT + (size_t)t * Nn * Nn + n;       // [m][n], n per-lane
    for (int m4 = 0; m4 < Nn; m4 += 4) {
        // score phase: 8 independent FMA chains (even/odd c split)
        float s0 = 0.f, s1 = 0.f, s2 = 0.f, s3 = 0.f;
        float u0 = 0.f, u1 = 0.f, u2 = 0.f, u3 = 0.f;
        #pragma unroll
        for (int c = 0; c < 64; c += 2) {
            float4 v = *(const float4*)(xb + c * Nn + m4);
            float4 w = *(const float4*)(xb + (c + 1) * Nn + m4);
            s0 += row[c] * v.x;     s1 += row[c] * v.y;
            s2 += row[c] * v.z;     s3 += row[c] * v.w;
            u0 += row[c + 1] * w.x; u1 += row[c + 1] * w.y;
            u2 += row[c + 1] * w.z; u3 += row[c + 1] * w.w;
        }
        float p0 = __expf((s0 + u0) * 0.125f), p1 = __expf((s1 + u1) * 0.125f);
        float p2 = __expf((s2 + u2) * 0.125f), p3 = __expf((s3 + u3) * 0.125f);
        sumexp += (p0 + p1) + (p2 + p3);
        float e0 = ehT[(m4 + 0) * Nn];
        float e1 = ehT[(m4 + 1) * Nn];
        float e2 = ehT[(m4 + 2) * Nn];
        float e3 = ehT[(m4 + 3) * Nn];
        asm volatile("" ::: "memory");   // block CSE of the 64 float4 re-loads
        #pragma unroll
        for (int c = 0; c < 64; ++c) {
            float4 v = *(const float4*)(xb + c * Nn + m4);
            accd[c] += p0 * v.x + p1 * v.y + p2 * v.z + p3 * v.w;
            accs[c] += e0 * v.x + e1 * v.y + e2 * v.z + e3 * v.w;
        }
    }
    float invd = 0.475f / sumexp;
    #pragma unroll
    for (int c = 0; c < 64; ++c) {
        accd[c] *= invd; accs[c] *= 0.475f; row[c] *= 0.05f;
    }
    const float* Wst = Ws + t * Hh * Cc;
    const float* Wdt = Wd + t * Hh * Cc;
    #pragma unroll 2
    for (int h = 0; h < Hh; ++h) {
        float a = 0.05f * b0[h] + 0.475f * bs[t * Hh + h] + 0.475f * bd[t * Hh + h];
        const float* w0r = W0 + h * Cc;
        const float* wsr = Wst + h * Cc;
        const float* wdr = Wdt + h * Cc;
        #pragma unroll
        for (int c = 0; c < 64; ++c)
            a += row[c] * w0r[c] + accs[c] * wsr[c] + accd[c] * wdr[c];
        sm[threadIdx.x * 65 + h] = a;
    }
    __syncthreads();
    float* Fb = F + ((size_t)(b * Tt + t) * Nn + nq * 128) * Hh;
    for (int i = threadIdx.x; i < 128 * 64; i += 128) {
        int nl = i >> 6, h = i & 63;
        Fb[i] = sm[nl * 65 + h];
    }
}

// ---------------------------------------------------------------------------
// K4: multi-scale grouped conv over t + GN statistics
__global__ void k4_conv(const float* __restrict__ F,
                        const float* __restrict__ w3, const float* __restrict__ w5,
                        const float* __restrict__ w7, const float* __restrict__ w9,
                        const float* __restrict__ cb,
                        float* __restrict__ xc, float* __restrict__ stats) {
    __shared__ float fl[2 * Tt * Hh];   // [t][nl][h] = 1536
    __shared__ float sstat[64];
    int blk = blockIdx.x;               // B * N/2 = 4096
    int b = blk >> 8; int n0 = (blk & 255) * 2;
    int tid = threadIdx.x;
    if (tid < 64) sstat[tid] = 0.f;
    for (int i = tid; i < 1536; i += 256) {
        int t = i >> 7; int r = i & 127;
        fl[i] = F[(size_t)(b * Tt + t) * Nn * Hh + n0 * Hh + r];
    }
    __syncthreads();
    int nl = tid >> 7; int co = tid & 127;
    int g = co >> 5;
    float a3[10], a5[8], a7[6], a9[4];
    {
        float c3 = cb[co], c5 = cb[128 + co], c7 = cb[256 + co], c9 = cb[384 + co];
        #pragma unroll
        for (int j = 0; j < 10; ++j) a3[j] = c3;
        #pragma unroll
        for (int j = 0; j < 8; ++j) a5[j] = c5;
        #pragma unroll
        for (int j = 0; j < 6; ++j) a7[j] = c7;
        #pragma unroll
        for (int j = 0; j < 4; ++j) a9[j] = c9;
    }
    for (int ci = 0; ci < 16; ++ci) {
        int cig = g * 16 + ci;
        float xr[12];
        #pragma unroll
        for (int tt = 0; tt < 12; ++tt) xr[tt] = fl[tt * 128 + nl * 64 + cig];
        const float* p3 = w3 + (co * 16 + ci) * 3;
        #pragma unroll
        for (int dt = 0; dt < 3; ++dt) {
            float wv = p3[dt];
            #pragma unroll
            for (int j = 0; j < 10; ++j) a3[j] += xr[j + dt] * wv;
        }
        const float* p5 = w5 + (co * 16 + ci) * 5;
        #pragma unroll
        for (int dt = 0; dt < 5; ++dt) {
            float wv = p5[dt];
            #pragma unroll
            for (int j = 0; j < 8; ++j) a5[j] += xr[j + dt] * wv;
        }
        const float* p7 = w7 + (co * 16 + ci) * 7;
        #pragma unroll
        for (int dt = 0; dt < 7; ++dt) {
            float wv = p7[dt];
            #pragma unroll
            for (int j = 0; j < 6; ++j) a7[j] += xr[j + dt] * wv;
        }
        const float* p9 = w9 + (co * 16 + ci) * 9;
        #pragma unroll
        for (int dt = 0; dt < 9; ++dt) {
            float wv = p9[dt];
            #pragma unroll
            for (int j = 0; j < 4; ++j) a9[j] += xr[j + dt] * wv;
        }
    }
    int pg = (co < 64) ? (co >> 4) : 4 + ((co - 64) >> 4);
    float* xcw = xc + ((size_t)(b * Nn + n0 + nl) * 128 + co) * 28;
    float su, sq;
    // scale 0 (k=3)
    su = 0.f; sq = 0.f;
    #pragma unroll
    for (int j = 0; j < 10; ++j) { float v = a3[j]; xcw[j] = v; su += v; sq += v * v; }
    #pragma unroll
    for (int off = 1; off < 16; off <<= 1) { su += __shfl_xor(su, off); sq += __shfl_xor(sq, off); }
    if ((tid & 15) == 0) { atomicAdd(&sstat[(0 * 8 + pg) * 2], su); atomicAdd(&sstat[(0 * 8 + pg) * 2 + 1], sq); }
    // scale 1 (k=5)
    su = 0.f; sq = 0.f;
    #pragma unroll
    for (int j = 0; j < 8; ++j) { float v = a5[j]; xcw[10 + j] = v; su += v; sq += v * v; }
    #pragma unroll
    for (int off = 1; off < 16; off <<= 1) { su += __shfl_xor(su, off); sq += __shfl_xor(sq, off); }
    if ((tid & 15) == 0) { atomicAdd(&sstat[(1 * 8 + pg) * 2], su); atomicAdd(&sstat[(1 * 8 + pg) * 2 + 1], sq); }
    // scale 2 (k=7)
    su = 0.f; sq = 0.f;
    #pragma unroll
    for (int j = 0; j < 6; ++j) { float v = a7[j]; xcw[18 + j] = v; su += v; sq += v * v; }
    #pragma unroll
    for (int off = 1; off < 16; off <<= 1) { su += __shfl_xor(su, off); sq += __shfl_xor(sq, off); }
    if ((tid & 15) == 0) { atomicAdd(&sstat[(2 * 8 + pg) * 2], su); atomicAdd(&sstat[(2 * 8 + pg) * 2 + 1], sq); }
    // scale 3 (k=9)
    su = 0.f; sq = 0.f;
    #pragma unroll
    for (int j = 0; j < 4; ++j) { float v = a9[j]; xcw[24 + j] = v; su += v; sq += v * v; }
    #pragma unroll
    for (int off = 1; off < 16; off <<= 1) { su += __shfl_xor(su, off); sq += __shfl_xor(sq, off); }
    if ((tid & 15) == 0) { atomicAdd(&sstat[(3 * 8 + pg) * 2], su); atomicAdd(&sstat[(3 * 8 + pg) * 2 + 1], sq); }
    __syncthreads();
    if (tid < 64) {
        int s = tid >> 4; int pgq = (tid >> 1) & 7; int st = tid & 1;
        atomicAdd(&stats[((s * Bb + b) * 8 + pgq) * 2 + st], sstat[(s * 8 + pgq) * 2 + st]);
    }
}

// ---------------------------------------------------------------------------
// K5: GN + Mish*Hardtanh + fc + residual + LN -> out[b][n][h][t]
__global__ __launch_bounds__(256) void k5_final(
                         const float* __restrict__ xc, const float* __restrict__ stats,
                         const float* __restrict__ x,
                         const float* __restrict__ gpw, const float* __restrict__ gpb,
                         const float* __restrict__ gqw, const float* __restrict__ gqb,
                         const float* __restrict__ fcw, const float* __restrict__ fcb,
                         const float* __restrict__ resT, const float* __restrict__ rb,
                         const float* __restrict__ lnw, const float* __restrict__ lnb,
                         float* __restrict__ out) {
    int blk = blockIdx.x;               // 2048 = B * N/4
    int b = blk >> 7; int n = (blk & 127) * 4 + (threadIdx.x >> 6);
    int h = threadIdx.x & 63;
    int pg = h >> 4;
    const int TkA[4] = {10, 8, 6, 4};
    float mu_p[4], rs_p[4], mu_q[4], rs_q[4];
    #pragma unroll
    for (int s = 0; s < 4; ++s) {
        float cnt = 16.f * 512.f * (float)TkA[s];
        float su = stats[((s * Bb + b) * 8 + pg) * 2];
        float sq = stats[((s * Bb + b) * 8 + pg) * 2 + 1];
        float mu = su / cnt; float var = sq / cnt - mu * mu;
        mu_p[s] = mu; rs_p[s] = rsqrtf(var + 1e-5f);
        su = stats[((s * Bb + b) * 8 + 4 + pg) * 2];
        sq = stats[((s * Bb + b) * 8 + 4 + pg) * 2 + 1];
        mu = su / cnt; var = sq / cnt - mu * mu;
        mu_q[s] = mu; rs_q[s] = rsqrtf(var + 1e-5f);
    }
    const float* xcp = xc + ((size_t)(b * Nn + n) * 128 + h) * 28;
    const float* xcq = xcp + 64 * 28;
    float pb_[28], qb_[28];
    {
        const float4* p4 = (const float4*)xcp;
        const float4* q4 = (const float4*)xcq;
        #pragma unroll
        for (int j = 0; j < 7; ++j) {
            float4 a = p4[j];
            pb_[j*4] = a.x; pb_[j*4+1] = a.y; pb_[j*4+2] = a.z; pb_[j*4+3] = a.w;
            float4 c = q4[j];
            qb_[j*4] = c.x; qb_[j*4+1] = c.y; qb_[j*4+2] = c.z; qb_[j*4+3] = c.w;
        }
    }
    float tc[28];
    int off = 0;
    #pragma unroll
    for (int s = 0; s < 4; ++s) {
        float pw = gpw[s * 64 + h], pbv = gpb[s * 64 + h];
        float qw = gqw[s * 64 + h], qbv = gqb[s * 64 + h];
        #pragma unroll
        for (int j = 0; j < 10; ++j) {
            if (j < TkA[s]) {
                float p = (pb_[off + j] - mu_p[s]) * rs_p[s] * pw + pbv;
                float q = (qb_[off + j] - mu_q[s]) * rs_q[s] * qw + qbv;
                // mish(p) = p * tanh(softplus(p)); tanh(sp) = (z^2-1)/(z^2+1), z = 1+e^p
                float mish;
                if (p > 20.f) mish = p;
                else { float z = 1.f + __expf(p); float z2 = z * z; mish = p * (z2 - 1.f) / (z2 + 1.f); }
                float gate = fminf(fmaxf(q, 0.f), 1.f);
                tc[off + j] = mish * gate;
            }
        }
        off += TkA[s];
    }
    float o[12];
    #pragma unroll
    for (int t = 0; t < 12; ++t) {
        float a = fcb[t];
        #pragma unroll
        for (int k = 0; k < 28; ++k) a += tc[k] * fcw[t * 28 + k];
        o[t] = fmaxf(a, 0.f);
    }
    const float* xr = x + (size_t)(b * Nn + n) * CT;
    float res[12];
    float rbv = rb[h];
    #pragma unroll
    for (int t = 0; t < 12; ++t) res[t] = rbv;
    for (int c = 0; c < 64; ++c) {
        float rv = resT[c * 64 + h];
        #pragma unroll
        for (int t = 0; t < 12; ++t) res[t] += xr[c * 12 + t] * rv;
    }
    float y[12];
    #pragma unroll
    for (int t = 0; t < 12; ++t) y[t] = fmaxf(res[t] + o[t], 0.f);
    float lw = lnw[h], lb = lnb[h];
    float* op = out + ((size_t)(b * Nn + n) * Hh + h) * Tt;
    #pragma unroll
    for (int t = 0; t < 12; ++t) {
        float s1 = y[t], s2 = y[t] * y[t];
        #pragma unroll
        for (int o2 = 32; o2 > 0; o2 >>= 1) {
            s1 += __shfl_xor(s1, o2);
            s2 += __shfl_xor(s2, o2);
        }
        float mu = s1 * (1.f / 64.f);
        float var = s2 * (1.f / 64.f) - mu * mu;
        op[t] = (y[t] - mu) * rsqrtf(var + 1e-5f) * lw + lb;
    }
}

// ---------------------------------------------------------------------------
extern "C" void kernel_launch(void* const* d_in, const int* in_sizes, int n_in,
                              void* d_out, int out_size, void* d_ws, size_t ws_size,
                              hipStream_t stream) {
    const float* x    = (const float*)d_in[0];
    const float* adj  = (const float*)d_in[1];
    const float* U1   = (const float*)d_in[2];
    const float* U2   = (const float*)d_in[3];
    const float* U3   = (const float*)d_in[4];
    const float* be   = (const float*)d_in[5];
    const float* Ve   = (const float*)d_in[6];
    const float* W0   = (const float*)d_in[7];
    const float* b0   = (const float*)d_in[8];
    const float* masks= (const float*)d_in[9];
    const float* Ws   = (const float*)d_in[10];
    const float* bs   = (const float*)d_in[11];
    const float* Wd   = (const float*)d_in[12];
    const float* bd   = (const float*)d_in[13];
    const float* w3   = (const float*)d_in[14];
    const float* w5   = (const float*)d_in[15];
    const float* w7   = (const float*)d_in[16];
    const float* w9   = (const float*)d_in[17];
    const float* cb   = (const float*)d_in[18];
    const float* gpw  = (const float*)d_in[19];
    const float* gpb  = (const float*)d_in[20];
    const float* gqw  = (const float*)d_in[21];
    const float* gqb  = (const float*)d_in[22];
    const float* fcw  = (const float*)d_in[23];
    const float* fcb  = (const float*)d_in[24];
    const float* rw   = (const float*)d_in[25];
    const float* rb   = (const float*)d_in[26];
    const float* lnw  = (const float*)d_in[27];
    const float* lnb  = (const float*)d_in[28];
    float* out = (float*)d_out;
    float* ws  = (float*)d_ws;

    float* tmp1  = ws;                  // 12288
    float* stats = ws + 12288;          // 1024
    float* At    = ws + 13312;          // 2304
    float* rhs   = ws + 15616;          // 98304
    float* resT  = ws + 113920;         // 4096
    float* xtT   = ws + 118016;         // 6291456
    float* enhT  = ws + 6409472;        // 3145728
    float* F     = ws + 9555200;        // 6291456
    float* xc    = ws + 15846656;       // 29360128  (end: 45206784 floats = 181 MB)

    hipMemsetAsync(ws, 0, 13312 * sizeof(float), stream);  // tmp1 + stats

    k0_rest<<<16, 256, 0, stream>>>(rw, resT);
    k1a_tmp1<<<192, 256, 0, stream>>>(x, U1, tmp1);
    k1b_rhs<<<384, 256, 0, stream>>>(x, U3, rhs);
    k2b_enh<<<3072, 256, 0, stream>>>(adj, masks, enhT);
    k1c_att<<<16, 256, 0, stream>>>(tmp1, rhs, U2, be, Ve, At);
    k2_xtt<<<2048, 256, 0, stream>>>(x, At, xtT);
    k3_gcn<<<768, 128, 0, stream>>>(xtT, enhT, W0, b0, Ws, bs, Wd, bd, F);
    k4_conv<<<4096, 256, 0, stream>>>(F, w3, w5, w7, w9, cb, xc, stats);
    k5_final<<<2048, 256, 0, stream>>>(xc, stats, x, gpw, gpb, gqw, gqb,
                                       fcw, fcb, resT, rb, lnw, lnb, out);
}

// Round 4
// 1910.582 us; speedup vs baseline: 1.1951x; 1.1951x over previous
//
#include <hip/hip_runtime.h>

// Shapes
constexpr int Bb = 16, Nn = 512, Cc = 64, Tt = 12, Hh = 64;
constexpr int NCT = Nn * Cc * Tt;     // 393216
constexpr int CT  = Cc * Tt;          // 768

// ---------------------------------------------------------------------------
// K0: transpose res_w [H][C] -> resT [C][H]
__global__ void k0_rest(const float* __restrict__ rw, float* __restrict__ resT) {
    int i = blockIdx.x * 256 + threadIdx.x;        // i = h*64 + c
    if (i < Hh * Cc) {
        int h = i >> 6, c = i & 63;
        resT[c * 64 + h] = rw[i];
    }
}

// ---------------------------------------------------------------------------
// K1a: tmp1[b][c*12+t] = sum_n x[b,n,c,t] * U1[n]   (partial over n-chunk, atomic)
__global__ void k1a_tmp1(const float* __restrict__ x, const float* __restrict__ U1,
                         float* __restrict__ tmp1) {
    int blk = blockIdx.x;                 // 16 * 3 * 4 = 192
    int b = blk / 12; int r = blk % 12;
    int ctb = r >> 2; int nch = r & 3;
    int ct = ctb * 256 + threadIdx.x;
    const float* xb = x + (size_t)b * NCT;
    float acc = 0.f;
    int n0 = nch * 128;
    for (int n = n0; n < n0 + 128; ++n)
        acc += xb[n * CT + ct] * U1[n];
    atomicAdd(&tmp1[b * CT + ct], acc);
}

// K1b: rhs[b][n][t] = sum_c U3[c] * x[b,n,c,t]
__global__ void k1b_rhs(const float* __restrict__ x, const float* __restrict__ U3,
                        float* __restrict__ rhs) {
    int idx = blockIdx.x * 256 + threadIdx.x;   // B*N*T = 98304
    int b = idx / (Nn * Tt);
    int r = idx % (Nn * Tt);
    int n = r / Tt; int t = r % Tt;
    const float* xr = x + (size_t)b * NCT + n * CT + t;
    float a = 0.f;
    for (int c = 0; c < Cc; ++c) a += xr[c * Tt] * U3[c];
    rhs[idx] = a;
}

// K1c: per-batch: lhs, product, E, softmax -> At[b][12][12]
__global__ void k1c_att(const float* __restrict__ tmp1, const float* __restrict__ rhs,
                        const float* __restrict__ U2, const float* __restrict__ be,
                        const float* __restrict__ Ve, float* __restrict__ At) {
    __shared__ float t1[CT];
    __shared__ float rh[Nn * Tt];
    __shared__ float lh[Tt * Nn];
    __shared__ float sp[144];
    __shared__ float Ee[144];
    int b = blockIdx.x, tid = threadIdx.x;
    for (int i = tid; i < CT; i += 256) t1[i] = tmp1[b * CT + i];
    for (int i = tid; i < Nn * Tt; i += 256) rh[i] = rhs[b * Nn * Tt + i];
    __syncthreads();
    for (int nn = tid; nn < Nn; nn += 256) {
        float l[Tt];
        #pragma unroll
        for (int t = 0; t < Tt; ++t) l[t] = 0.f;
        for (int c = 0; c < Cc; ++c) {
            float u2 = U2[c * Nn + nn];
            #pragma unroll
            for (int t = 0; t < Tt; ++t) l[t] += t1[c * Tt + t] * u2;
        }
        #pragma unroll
        for (int t = 0; t < Tt; ++t) lh[t * Nn + nn] = l[t];
    }
    __syncthreads();
    if (tid < 144) {
        int t = tid / 12, s2 = tid % 12;
        float a = 0.f;
        for (int nn = 0; nn < Nn; ++nn) a += lh[t * Nn + nn] * rh[nn * Tt + s2];
        a += be[tid];
        sp[tid] = 1.f / (1.f + __expf(-a));
    }
    __syncthreads();
    if (tid < 144) {
        int i = tid / 12, k = tid % 12;
        float a = 0.f;
        #pragma unroll
        for (int j = 0; j < 12; ++j) a += Ve[i * 12 + j] * sp[j * 12 + k];
        Ee[tid] = a;
    }
    __syncthreads();
    if (tid < 12) {
        int k = tid;
        float mx = -1e30f;
        #pragma unroll
        for (int i = 0; i < 12; ++i) mx = fmaxf(mx, Ee[i * 12 + k]);
        float su = 0.f; float ex[12];
        #pragma unroll
        for (int i = 0; i < 12; ++i) { ex[i] = __expf(Ee[i * 12 + k] - mx); su += ex[i]; }
        float inv = 1.f / su;
        #pragma unroll
        for (int i = 0; i < 12; ++i) At[b * 144 + i * 12 + k] = ex[i] * inv;
    }
}

// ---------------------------------------------------------------------------
// K2: xtT[b][t][c][n] = sum_tau x[b,n,c,tau] * At[b,tau,t]
__global__ void k2_xtt(const float* __restrict__ x, const float* __restrict__ At,
                       float* __restrict__ xtT) {
    int idx = blockIdx.x * 256 + threadIdx.x;  // B*C*N = 524288, n fastest
    int n = idx & 511; int c = (idx >> 9) & 63; int b = idx >> 15;
    const float* xr = x + (size_t)((b * Nn + n) * Cc + c) * Tt;
    float xv[Tt];
    {
        const float4* x4 = (const float4*)xr;
        float4 a0 = x4[0], a1 = x4[1], a2 = x4[2];
        xv[0]=a0.x; xv[1]=a0.y; xv[2]=a0.z; xv[3]=a0.w;
        xv[4]=a1.x; xv[5]=a1.y; xv[6]=a1.z; xv[7]=a1.w;
        xv[8]=a2.x; xv[9]=a2.y; xv[10]=a2.z; xv[11]=a2.w;
    }
    const float* Ab = At + b * 144;
    for (int t = 0; t < Tt; ++t) {
        float a = 0.f;
        #pragma unroll
        for (int u = 0; u < Tt; ++u) a += xv[u] * Ab[u * 12 + t];
        xtT[((size_t)(b * Tt + t) * Cc + c) * Nn + n] = a;
    }
}

// K2b: enhT[t][m][n] = adj[n][m] * sigmoid(masks[t][n][m])  (tiled transpose)
__global__ void k2b_enh(const float* __restrict__ adj, const float* __restrict__ masks,
                        float* __restrict__ enhT) {
    __shared__ float tile[32][33];
    int blk = blockIdx.x;              // 12 * 16 * 16 = 3072
    int t = blk >> 8; int r = blk & 255;
    int n0 = (r >> 4) * 32; int m0 = (r & 15) * 32;
    int tx = threadIdx.x & 31; int ty = threadIdx.x >> 5;   // ty 0..7
    #pragma unroll
    for (int i = 0; i < 4; ++i) {
        int nl = ty + 8 * i;
        float a  = adj[(n0 + nl) * Nn + m0 + tx];
        float mk = masks[t * Nn * Nn + (n0 + nl) * Nn + m0 + tx];
        tile[nl][tx] = a / (1.f + __expf(-mk));
    }
    __syncthreads();
    #pragma unroll
    for (int i = 0; i < 4; ++i) {
        int ml = ty + 8 * i;
        enhT[(size_t)(t * Nn + m0 + ml) * Nn + n0 + tx] = tile[tx][ml];
    }
}

// ---------------------------------------------------------------------------
// K3: c-split — each row n handled by a lane PAIR (lane, lane^32), each owning
// 32 of the 64 channels. Live state 96 floats/lane -> no spill; 1-wave blocks,
// grid 3072 -> 12 waves/CU.
__global__ __launch_bounds__(64, 3) void k3_gcn(
    const float* __restrict__ xtT, const float* __restrict__ enhT,
    const float* __restrict__ W0, const float* __restrict__ b0,
    const float* __restrict__ Ws, const float* __restrict__ bs,
    const float* __restrict__ Wd, const float* __restrict__ bd,
    float* __restrict__ F) {
    int blk = blockIdx.x;              // 3072 = B*T*16
    int seg = blk & 15; int t = (blk >> 4) % Tt; int b = blk / (Tt * 16);
    int lane = threadIdx.x;            // 0..63
    int half = lane >> 5;              // 0: c in [0,32), 1: c in [32,64)
    int r = lane & 31;
    int n = seg * 32 + r;
    int c0 = half * 32;
    const float* xb = xtT + (size_t)(b * Tt + t) * Cc * Nn;  // [C][N]
    float row[32], accd[32], accs[32];
    #pragma unroll
    for (int j = 0; j < 32; ++j) row[j] = xb[(c0 + j) * Nn + n];
    #pragma unroll
    for (int j = 0; j < 32; ++j) { accd[j] = 0.f; accs[j] = 0.f; }
    float sumexp = 0.f;
    const float* ehT = enhT + (size_t)t * Nn * Nn + n;       // [m][n], n per-lane
    for (int m4 = 0; m4 < Nn; m4 += 4) {
        // half-dot over my 32 channels, 4 m's at once
        float s0 = 0.f, s1 = 0.f, s2 = 0.f, s3 = 0.f;
        #pragma unroll
        for (int j = 0; j < 32; ++j) {
            float4 v = *(const float4*)(xb + (c0 + j) * Nn + m4);
            float rj = row[j];
            s0 += rj * v.x; s1 += rj * v.y; s2 += rj * v.z; s3 += rj * v.w;
        }
        // combine halves -> full 64-c dot (both halves get identical values)
        s0 += __shfl_xor(s0, 32); s1 += __shfl_xor(s1, 32);
        s2 += __shfl_xor(s2, 32); s3 += __shfl_xor(s3, 32);
        float p0 = __expf(s0 * 0.125f), p1 = __expf(s1 * 0.125f);
        float p2 = __expf(s2 * 0.125f), p3 = __expf(s3 * 0.125f);
        sumexp += (p0 + p1) + (p2 + p3);
        float e0 = ehT[(m4 + 0) * Nn];
        float e1 = ehT[(m4 + 1) * Nn];
        float e2 = ehT[(m4 + 2) * Nn];
        float e3 = ehT[(m4 + 3) * Nn];
        asm volatile("" ::: "memory");   // keep the two X passes as re-loads (no CSE buffering)
        #pragma unroll
        for (int j = 0; j < 32; ++j) {
            float4 v = *(const float4*)(xb + (c0 + j) * Nn + m4);
            accd[j] += p0 * v.x + p1 * v.y + p2 * v.z + p3 * v.w;
            accs[j] += e0 * v.x + e1 * v.y + e2 * v.z + e3 * v.w;
        }
    }
    float invd = 0.475f / sumexp;
    #pragma unroll
    for (int j = 0; j < 32; ++j) {
        accd[j] *= invd; accs[j] *= 0.475f; row[j] *= 0.05f;
    }
    const float* Wst = Ws + t * Hh * Cc;
    const float* Wdt = Wd + t * Hh * Cc;
    float* Fp = F + ((size_t)(b * Tt + t) * Nn + n) * Hh;
    for (int hb = 0; hb < 16; ++hb) {
        float o[4];
        #pragma unroll
        for (int k = 0; k < 4; ++k) {
            int h = hb * 4 + k;
            float a = (half == 0)
                ? (0.05f * b0[h] + 0.475f * (bs[t * Hh + h] + bd[t * Hh + h]))
                : 0.f;
            const float* w0r = W0 + h * Cc + c0;
            const float* wsr = Wst + h * Cc + c0;
            const float* wdr = Wdt + h * Cc + c0;
            #pragma unroll
            for (int j = 0; j < 32; ++j)
                a += row[j] * w0r[j] + accs[j] * wsr[j] + accd[j] * wdr[j];
            a += __shfl_xor(a, 32);    // combine c-halves
            o[k] = a;
        }
        if ((hb >> 3) == half)
            *(float4*)(Fp + hb * 4) = make_float4(o[0], o[1], o[2], o[3]);
    }
}

// ---------------------------------------------------------------------------
// K4: multi-scale grouped conv over t + GN statistics
__global__ void k4_conv(const float* __restrict__ F,
                        const float* __restrict__ w3, const float* __restrict__ w5,
                        const float* __restrict__ w7, const float* __restrict__ w9,
                        const float* __restrict__ cb,
                        float* __restrict__ xc, float* __restrict__ stats) {
    __shared__ float fl[2 * Tt * Hh];   // [t][nl][h] = 1536
    __shared__ float sstat[64];
    int blk = blockIdx.x;               // B * N/2 = 4096
    int b = blk >> 8; int n0 = (blk & 255) * 2;
    int tid = threadIdx.x;
    if (tid < 64) sstat[tid] = 0.f;
    for (int i = tid; i < 1536; i += 256) {
        int t = i >> 7; int r = i & 127;
        fl[i] = F[(size_t)(b * Tt + t) * Nn * Hh + n0 * Hh + r];
    }
    __syncthreads();
    int nl = tid >> 7; int co = tid & 127;
    int g = co >> 5;
    float a3[10], a5[8], a7[6], a9[4];
    {
        float c3 = cb[co], c5 = cb[128 + co], c7 = cb[256 + co], c9 = cb[384 + co];
        #pragma unroll
        for (int j = 0; j < 10; ++j) a3[j] = c3;
        #pragma unroll
        for (int j = 0; j < 8; ++j) a5[j] = c5;
        #pragma unroll
        for (int j = 0; j < 6; ++j) a7[j] = c7;
        #pragma unroll
        for (int j = 0; j < 4; ++j) a9[j] = c9;
    }
    for (int ci = 0; ci < 16; ++ci) {
        int cig = g * 16 + ci;
        float xr[12];
        #pragma unroll
        for (int tt = 0; tt < 12; ++tt) xr[tt] = fl[tt * 128 + nl * 64 + cig];
        const float* p3 = w3 + (co * 16 + ci) * 3;
        #pragma unroll
        for (int dt = 0; dt < 3; ++dt) {
            float wv = p3[dt];
            #pragma unroll
            for (int j = 0; j < 10; ++j) a3[j] += xr[j + dt] * wv;
        }
        const float* p5 = w5 + (co * 16 + ci) * 5;
        #pragma unroll
        for (int dt = 0; dt < 5; ++dt) {
            float wv = p5[dt];
            #pragma unroll
            for (int j = 0; j < 8; ++j) a5[j] += xr[j + dt] * wv;
        }
        const float* p7 = w7 + (co * 16 + ci) * 7;
        #pragma unroll
        for (int dt = 0; dt < 7; ++dt) {
            float wv = p7[dt];
            #pragma unroll
            for (int j = 0; j < 6; ++j) a7[j] += xr[j + dt] * wv;
        }
        const float* p9 = w9 + (co * 16 + ci) * 9;
        #pragma unroll
        for (int dt = 0; dt < 9; ++dt) {
            float wv = p9[dt];
            #pragma unroll
            for (int j = 0; j < 4; ++j) a9[j] += xr[j + dt] * wv;
        }
    }
    int pg = (co < 64) ? (co >> 4) : 4 + ((co - 64) >> 4);
    float* xcw = xc + ((size_t)(b * Nn + n0 + nl) * 128 + co) * 28;
    float su, sq;
    // scale 0 (k=3)
    su = 0.f; sq = 0.f;
    #pragma unroll
    for (int j = 0; j < 10; ++j) { float v = a3[j]; xcw[j] = v; su += v; sq += v * v; }
    #pragma unroll
    for (int off = 1; off < 16; off <<= 1) { su += __shfl_xor(su, off); sq += __shfl_xor(sq, off); }
    if ((tid & 15) == 0) { atomicAdd(&sstat[(0 * 8 + pg) * 2], su); atomicAdd(&sstat[(0 * 8 + pg) * 2 + 1], sq); }
    // scale 1 (k=5)
    su = 0.f; sq = 0.f;
    #pragma unroll
    for (int j = 0; j < 8; ++j) { float v = a5[j]; xcw[10 + j] = v; su += v; sq += v * v; }
    #pragma unroll
    for (int off = 1; off < 16; off <<= 1) { su += __shfl_xor(su, off); sq += __shfl_xor(sq, off); }
    if ((tid & 15) == 0) { atomicAdd(&sstat[(1 * 8 + pg) * 2], su); atomicAdd(&sstat[(1 * 8 + pg) * 2 + 1], sq); }
    // scale 2 (k=7)
    su = 0.f; sq = 0.f;
    #pragma unroll
    for (int j = 0; j < 6; ++j) { float v = a7[j]; xcw[18 + j] = v; su += v; sq += v * v; }
    #pragma unroll
    for (int off = 1; off < 16; off <<= 1) { su += __shfl_xor(su, off); sq += __shfl_xor(sq, off); }
    if ((tid & 15) == 0) { atomicAdd(&sstat[(2 * 8 + pg) * 2], su); atomicAdd(&sstat[(2 * 8 + pg) * 2 + 1], sq); }
    // scale 3 (k=9)
    su = 0.f; sq = 0.f;
    #pragma unroll
    for (int j = 0; j < 4; ++j) { float v = a9[j]; xcw[24 + j] = v; su += v; sq += v * v; }
    #pragma unroll
    for (int off = 1; off < 16; off <<= 1) { su += __shfl_xor(su, off); sq += __shfl_xor(sq, off); }
    if ((tid & 15) == 0) { atomicAdd(&sstat[(3 * 8 + pg) * 2], su); atomicAdd(&sstat[(3 * 8 + pg) * 2 + 1], sq); }
    __syncthreads();
    if (tid < 64) {
        int s = tid >> 4; int pgq = (tid >> 1) & 7; int st = tid & 1;
        atomicAdd(&stats[((s * Bb + b) * 8 + pgq) * 2 + st], sstat[(s * 8 + pgq) * 2 + st]);
    }
}

// ---------------------------------------------------------------------------
// K5: GN + Mish*Hardtanh + fc + residual + LN -> out[b][n][h][t]
__global__ __launch_bounds__(256) void k5_final(
                         const float* __restrict__ xc, const float* __restrict__ stats,
                         const float* __restrict__ x,
                         const float* __restrict__ gpw, const float* __restrict__ gpb,
                         const float* __restrict__ gqw, const float* __restrict__ gqb,
                         const float* __restrict__ fcw, const float* __restrict__ fcb,
                         const float* __restrict__ resT, const float* __restrict__ rb,
                         const float* __restrict__ lnw, const float* __restrict__ lnb,
                         float* __restrict__ out) {
    int blk = blockIdx.x;               // 2048 = B * N/4
    int b = blk >> 7; int n = (blk & 127) * 4 + (threadIdx.x >> 6);
    int h = threadIdx.x & 63;
    int pg = h >> 4;
    const int TkA[4] = {10, 8, 6, 4};
    float mu_p[4], rs_p[4], mu_q[4], rs_q[4];
    #pragma unroll
    for (int s = 0; s < 4; ++s) {
        float cnt = 16.f * 512.f * (float)TkA[s];
        float su = stats[((s * Bb + b) * 8 + pg) * 2];
        float sq = stats[((s * Bb + b) * 8 + pg) * 2 + 1];
        float mu = su / cnt; float var = sq / cnt - mu * mu;
        mu_p[s] = mu; rs_p[s] = rsqrtf(var + 1e-5f);
        su = stats[((s * Bb + b) * 8 + 4 + pg) * 2];
        sq = stats[((s * Bb + b) * 8 + 4 + pg) * 2 + 1];
        mu = su / cnt; var = sq / cnt - mu * mu;
        mu_q[s] = mu; rs_q[s] = rsqrtf(var + 1e-5f);
    }
    const float* xcp = xc + ((size_t)(b * Nn + n) * 128 + h) * 28;
    const float* xcq = xcp + 64 * 28;
    float pb_[28], qb_[28];
    {
        const float4* p4 = (const float4*)xcp;
        const float4* q4 = (const float4*)xcq;
        #pragma unroll
        for (int j = 0; j < 7; ++j) {
            float4 a = p4[j];
            pb_[j*4] = a.x; pb_[j*4+1] = a.y; pb_[j*4+2] = a.z; pb_[j*4+3] = a.w;
            float4 c = q4[j];
            qb_[j*4] = c.x; qb_[j*4+1] = c.y; qb_[j*4+2] = c.z; qb_[j*4+3] = c.w;
        }
    }
    float tc[28];
    int off = 0;
    #pragma unroll
    for (int s = 0; s < 4; ++s) {
        float pw = gpw[s * 64 + h], pbv = gpb[s * 64 + h];
        float qw = gqw[s * 64 + h], qbv = gqb[s * 64 + h];
        #pragma unroll
        for (int j = 0; j < 10; ++j) {
            if (j < TkA[s]) {
                float p = (pb_[off + j] - mu_p[s]) * rs_p[s] * pw + pbv;
                float q = (qb_[off + j] - mu_q[s]) * rs_q[s] * qw + qbv;
                // mish(p) = p * tanh(softplus(p)); tanh(sp) = (z^2-1)/(z^2+1), z = 1+e^p
                float mish;
                if (p > 20.f) mish = p;
                else { float z = 1.f + __expf(p); float z2 = z * z; mish = p * (z2 - 1.f) / (z2 + 1.f); }
                float gate = fminf(fmaxf(q, 0.f), 1.f);
                tc[off + j] = mish * gate;
            }
        }
        off += TkA[s];
    }
    float o[12];
    #pragma unroll
    for (int t = 0; t < 12; ++t) {
        float a = fcb[t];
        #pragma unroll
        for (int k = 0; k < 28; ++k) a += tc[k] * fcw[t * 28 + k];
        o[t] = fmaxf(a, 0.f);
    }
    const float* xr = x + (size_t)(b * Nn + n) * CT;
    float res[12];
    float rbv = rb[h];
    #pragma unroll
    for (int t = 0; t < 12; ++t) res[t] = rbv;
    for (int c = 0; c < 64; ++c) {
        float rv = resT[c * 64 + h];
        #pragma unroll
        for (int t = 0; t < 12; ++t) res[t] += xr[c * 12 + t] * rv;
    }
    float y[12];
    #pragma unroll
    for (int t = 0; t < 12; ++t) y[t] = fmaxf(res[t] + o[t], 0.f);
    float lw = lnw[h], lb = lnb[h];
    float* op = out + ((size_t)(b * Nn + n) * Hh + h) * Tt;
    #pragma unroll
    for (int t = 0; t < 12; ++t) {
        float s1 = y[t], s2 = y[t] * y[t];
        #pragma unroll
        for (int o2 = 32; o2 > 0; o2 >>= 1) {
            s1 += __shfl_xor(s1, o2);
            s2 += __shfl_xor(s2, o2);
        }
        float mu = s1 * (1.f / 64.f);
        float var = s2 * (1.f / 64.f) - mu * mu;
        op[t] = (y[t] - mu) * rsqrtf(var + 1e-5f) * lw + lb;
    }
}

// ---------------------------------------------------------------------------
extern "C" void kernel_launch(void* const* d_in, const int* in_sizes, int n_in,
                              void* d_out, int out_size, void* d_ws, size_t ws_size,
                              hipStream_t stream) {
    const float* x    = (const float*)d_in[0];
    const float* adj  = (const float*)d_in[1];
    const float* U1   = (const float*)d_in[2];
    const float* U2   = (const float*)d_in[3];
    const float* U3   = (const float*)d_in[4];
    const float* be   = (const float*)d_in[5];
    const float* Ve   = (const float*)d_in[6];
    const float* W0   = (const float*)d_in[7];
    const float* b0   = (const float*)d_in[8];
    const float* masks= (const float*)d_in[9];
    const float* Ws   = (const float*)d_in[10];
    const float* bs   = (const float*)d_in[11];
    const float* Wd   = (const float*)d_in[12];
    const float* bd   = (const float*)d_in[13];
    const float* w3   = (const float*)d_in[14];
    const float* w5   = (const float*)d_in[15];
    const float* w7   = (const float*)d_in[16];
    const float* w9   = (const float*)d_in[17];
    const float* cb   = (const float*)d_in[18];
    const float* gpw  = (const float*)d_in[19];
    const float* gpb  = (const float*)d_in[20];
    const float* gqw  = (const float*)d_in[21];
    const float* gqb  = (const float*)d_in[22];
    const float* fcw  = (const float*)d_in[23];
    const float* fcb  = (const float*)d_in[24];
    const float* rw   = (const float*)d_in[25];
    const float* rb   = (const float*)d_in[26];
    const float* lnw  = (const float*)d_in[27];
    const float* lnb  = (const float*)d_in[28];
    float* out = (float*)d_out;
    float* ws  = (float*)d_ws;

    float* tmp1  = ws;                  // 12288
    float* stats = ws + 12288;          // 1024
    float* At    = ws + 13312;          // 2304
    float* rhs   = ws + 15616;          // 98304
    float* resT  = ws + 113920;         // 4096
    float* xtT   = ws + 118016;         // 6291456
    float* enhT  = ws + 6409472;        // 3145728
    float* F     = ws + 9555200;        // 6291456
    float* xc    = ws + 15846656;       // 29360128  (end: 45206784 floats = 181 MB)

    hipMemsetAsync(ws, 0, 13312 * sizeof(float), stream);  // tmp1 + stats

    k0_rest<<<16, 256, 0, stream>>>(rw, resT);
    k1a_tmp1<<<192, 256, 0, stream>>>(x, U1, tmp1);
    k1b_rhs<<<384, 256, 0, stream>>>(x, U3, rhs);
    k2b_enh<<<3072, 256, 0, stream>>>(adj, masks, enhT);
    k1c_att<<<16, 256, 0, stream>>>(tmp1, rhs, U2, be, Ve, At);
    k2_xtt<<<2048, 256, 0, stream>>>(x, At, xtT);
    k3_gcn<<<3072, 64, 0, stream>>>(xtT, enhT, W0, b0, Ws, bs, Wd, bd, F);
    k4_conv<<<4096, 256, 0, stream>>>(F, w3, w5, w7, w9, cb, xc, stats);
    k5_final<<<2048, 256, 0, stream>>>(xc, stats, x, gpw, gpb, gqw, gqb,
                                       fcw, fcb, resT, rb, lnw, lnb, out);
}

// Round 5
// 1243.795 us; speedup vs baseline: 1.8359x; 1.5361x over previous
//
#include <hip/hip_runtime.h>

// Shapes
constexpr int Bb = 16, Nn = 512, Cc = 64, Tt = 12, Hh = 64;
constexpr int NCT = Nn * Cc * Tt;     // 393216
constexpr int CT  = Cc * Tt;          // 768

// ---------------------------------------------------------------------------
// K0: transpose res_w [H][C] -> resT [C][H]
__global__ void k0_rest(const float* __restrict__ rw, float* __restrict__ resT) {
    int i = blockIdx.x * 256 + threadIdx.x;        // i = h*64 + c
    if (i < Hh * Cc) {
        int h = i >> 6, c = i & 63;
        resT[c * 64 + h] = rw[i];
    }
}

// ---------------------------------------------------------------------------
// K1a: tmp1[b][c*12+t] = sum_n x[b,n,c,t] * U1[n]   (partial over n-chunk, atomic)
__global__ void k1a_tmp1(const float* __restrict__ x, const float* __restrict__ U1,
                         float* __restrict__ tmp1) {
    int blk = blockIdx.x;                 // 16 * 3 * 4 = 192
    int b = blk / 12; int r = blk % 12;
    int ctb = r >> 2; int nch = r & 3;
    int ct = ctb * 256 + threadIdx.x;
    const float* xb = x + (size_t)b * NCT;
    float acc = 0.f;
    int n0 = nch * 128;
    for (int n = n0; n < n0 + 128; ++n)
        acc += xb[n * CT + ct] * U1[n];
    atomicAdd(&tmp1[b * CT + ct], acc);
}

// K1b: rhs[b][n][t] = sum_c U3[c] * x[b,n,c,t]
__global__ void k1b_rhs(const float* __restrict__ x, const float* __restrict__ U3,
                        float* __restrict__ rhs) {
    int idx = blockIdx.x * 256 + threadIdx.x;   // B*N*T = 98304
    int b = idx / (Nn * Tt);
    int r = idx % (Nn * Tt);
    int n = r / Tt; int t = r % Tt;
    const float* xr = x + (size_t)b * NCT + n * CT + t;
    float a = 0.f;
    for (int c = 0; c < Cc; ++c) a += xr[c * Tt] * U3[c];
    rhs[idx] = a;
}

// K1c: per-batch: lhs, product, E, softmax -> At[b][12][12]
__global__ void k1c_att(const float* __restrict__ tmp1, const float* __restrict__ rhs,
                        const float* __restrict__ U2, const float* __restrict__ be,
                        const float* __restrict__ Ve, float* __restrict__ At) {
    __shared__ float t1[CT];
    __shared__ float rh[Nn * Tt];
    __shared__ float lh[Tt * Nn];
    __shared__ float sp[144];
    __shared__ float Ee[144];
    int b = blockIdx.x, tid = threadIdx.x;
    for (int i = tid; i < CT; i += 256) t1[i] = tmp1[b * CT + i];
    for (int i = tid; i < Nn * Tt; i += 256) rh[i] = rhs[b * Nn * Tt + i];
    __syncthreads();
    for (int nn = tid; nn < Nn; nn += 256) {
        float l[Tt];
        #pragma unroll
        for (int t = 0; t < Tt; ++t) l[t] = 0.f;
        for (int c = 0; c < Cc; ++c) {
            float u2 = U2[c * Nn + nn];
            #pragma unroll
            for (int t = 0; t < Tt; ++t) l[t] += t1[c * Tt + t] * u2;
        }
        #pragma unroll
        for (int t = 0; t < Tt; ++t) lh[t * Nn + nn] = l[t];
    }
    __syncthreads();
    if (tid < 144) {
        int t = tid / 12, s2 = tid % 12;
        float a = 0.f;
        for (int nn = 0; nn < Nn; ++nn) a += lh[t * Nn + nn] * rh[nn * Tt + s2];
        a += be[tid];
        sp[tid] = 1.f / (1.f + __expf(-a));
    }
    __syncthreads();
    if (tid < 144) {
        int i = tid / 12, k = tid % 12;
        float a = 0.f;
        #pragma unroll
        for (int j = 0; j < 12; ++j) a += Ve[i * 12 + j] * sp[j * 12 + k];
        Ee[tid] = a;
    }
    __syncthreads();
    if (tid < 12) {
        int k = tid;
        float mx = -1e30f;
        #pragma unroll
        for (int i = 0; i < 12; ++i) mx = fmaxf(mx, Ee[i * 12 + k]);
        float su = 0.f; float ex[12];
        #pragma unroll
        for (int i = 0; i < 12; ++i) { ex[i] = __expf(Ee[i * 12 + k] - mx); su += ex[i]; }
        float inv = 1.f / su;
        #pragma unroll
        for (int i = 0; i < 12; ++i) At[b * 144 + i * 12 + k] = ex[i] * inv;
    }
}

// ---------------------------------------------------------------------------
// K2: xtT[b][t][c][n] = sum_tau x[b,n,c,tau] * At[b,tau,t]
__global__ void k2_xtt(const float* __restrict__ x, const float* __restrict__ At,
                       float* __restrict__ xtT) {
    int idx = blockIdx.x * 256 + threadIdx.x;  // B*C*N = 524288, n fastest
    int n = idx & 511; int c = (idx >> 9) & 63; int b = idx >> 15;
    const float* xr = x + (size_t)((b * Nn + n) * Cc + c) * Tt;
    float xv[Tt];
    {
        const float4* x4 = (const float4*)xr;
        float4 a0 = x4[0], a1 = x4[1], a2 = x4[2];
        xv[0]=a0.x; xv[1]=a0.y; xv[2]=a0.z; xv[3]=a0.w;
        xv[4]=a1.x; xv[5]=a1.y; xv[6]=a1.z; xv[7]=a1.w;
        xv[8]=a2.x; xv[9]=a2.y; xv[10]=a2.z; xv[11]=a2.w;
    }
    const float* Ab = At + b * 144;
    for (int t = 0; t < Tt; ++t) {
        float a = 0.f;
        #pragma unroll
        for (int u = 0; u < Tt; ++u) a += xv[u] * Ab[u * 12 + t];
        xtT[((size_t)(b * Tt + t) * Cc + c) * Nn + n] = a;
    }
}

// K2b: enhT[t][m][n] = adj[n][m] * sigmoid(masks[t][n][m])  (tiled transpose)
__global__ void k2b_enh(const float* __restrict__ adj, const float* __restrict__ masks,
                        float* __restrict__ enhT) {
    __shared__ float tile[32][33];
    int blk = blockIdx.x;              // 12 * 16 * 16 = 3072
    int t = blk >> 8; int r = blk & 255;
    int n0 = (r >> 4) * 32; int m0 = (r & 15) * 32;
    int tx = threadIdx.x & 31; int ty = threadIdx.x >> 5;   // ty 0..7
    #pragma unroll
    for (int i = 0; i < 4; ++i) {
        int nl = ty + 8 * i;
        float a  = adj[(n0 + nl) * Nn + m0 + tx];
        float mk = masks[t * Nn * Nn + (n0 + nl) * Nn + m0 + tx];
        tile[nl][tx] = a / (1.f + __expf(-mk));
    }
    __syncthreads();
    #pragma unroll
    for (int i = 0; i < 4; ++i) {
        int ml = ty + 8 * i;
        enhT[(size_t)(t * Nn + m0 + ml) * Nn + n0 + tx] = tile[tx][ml];
    }
}

// ---------------------------------------------------------------------------
// K3: LDS-staged. Block = 256 threads (4 waves) = 128 rows of one (b,t);
// lane pair (r, r+32) owns a row, each half 32 channels. x-slab streamed
// through a 16 KB LDS tile; score+acc read it as uniform broadcasts.
__global__ __launch_bounds__(256, 3) void k3_gcn(
    const float* __restrict__ xtT, const float* __restrict__ enhT,
    const float* __restrict__ W0, const float* __restrict__ b0,
    const float* __restrict__ Ws, const float* __restrict__ bs,
    const float* __restrict__ Wd, const float* __restrict__ bd,
    float* __restrict__ F) {
    __shared__ float xs[64][64];       // [c][m-tile] 16 KB
    int blk = blockIdx.x;              // 768 = B*T*4
    int seg = blk & 3; int t = (blk >> 2) % Tt; int b = blk / (Tt * 4);
    int tid = threadIdx.x;
    int lane = tid & 63;
    int w = tid >> 6;                  // wave 0..3
    int half = lane >> 5;              // 0: c in [0,32), 1: c in [32,64)
    int r = lane & 31;
    int n = seg * 128 + w * 32 + r;
    int c0 = half * 32;
    const float* xb = xtT + (size_t)(b * Tt + t) * Cc * Nn;  // [C][N]
    float row[32], accd[32], accs[32];
    #pragma unroll
    for (int j = 0; j < 32; ++j) row[j] = xb[(c0 + j) * Nn + n];
    #pragma unroll
    for (int j = 0; j < 32; ++j) { accd[j] = 0.f; accs[j] = 0.f; }
    float sumexp = 0.f;
    const float* ehT = enhT + (size_t)t * Nn * Nn + n;       // [m][n], n per-lane
    for (int m0 = 0; m0 < Nn; m0 += 64) {
        __syncthreads();               // previous tile fully consumed
        #pragma unroll
        for (int i = 0; i < 4; ++i) {
            int f = i * 256 + tid;     // float4 index 0..1023
            int c = f >> 4; int mi = (f & 15) * 4;
            *(float4*)&xs[c][mi] = *(const float4*)(xb + c * Nn + m0 + mi);
        }
        __syncthreads();
        for (int m4 = 0; m4 < 64; m4 += 4) {
            float s0 = 0.f, s1 = 0.f, s2 = 0.f, s3 = 0.f;
            #pragma unroll
            for (int j = 0; j < 32; ++j) {
                float4 v = *(const float4*)&xs[c0 + j][m4];
                float rj = row[j];
                s0 += rj * v.x; s1 += rj * v.y; s2 += rj * v.z; s3 += rj * v.w;
            }
            s0 += __shfl_xor(s0, 32); s1 += __shfl_xor(s1, 32);
            s2 += __shfl_xor(s2, 32); s3 += __shfl_xor(s3, 32);
            float p0 = __expf(s0 * 0.125f), p1 = __expf(s1 * 0.125f);
            float p2 = __expf(s2 * 0.125f), p3 = __expf(s3 * 0.125f);
            sumexp += (p0 + p1) + (p2 + p3);
            float e0 = ehT[(m0 + m4 + 0) * Nn];
            float e1 = ehT[(m0 + m4 + 1) * Nn];
            float e2 = ehT[(m0 + m4 + 2) * Nn];
            float e3 = ehT[(m0 + m4 + 3) * Nn];
            asm volatile("" ::: "memory");   // force LDS re-read (keep regs = 96 live)
            #pragma unroll
            for (int j = 0; j < 32; ++j) {
                float4 v = *(const float4*)&xs[c0 + j][m4];
                accd[j] += p0 * v.x + p1 * v.y + p2 * v.z + p3 * v.w;
                accs[j] += e0 * v.x + e1 * v.y + e2 * v.z + e3 * v.w;
            }
        }
    }
    float invd = 0.475f / sumexp;
    #pragma unroll
    for (int j = 0; j < 32; ++j) {
        accd[j] *= invd; accs[j] *= 0.475f; row[j] *= 0.05f;
    }
    const float* Wst = Ws + t * Hh * Cc;
    const float* Wdt = Wd + t * Hh * Cc;
    float* Fp = F + ((size_t)(b * Tt + t) * Nn + n) * Hh;
    for (int hb = 0; hb < 16; ++hb) {
        float o[4];
        #pragma unroll
        for (int k = 0; k < 4; ++k) {
            int h = hb * 4 + k;
            float a = (half == 0)
                ? (0.05f * b0[h] + 0.475f * (bs[t * Hh + h] + bd[t * Hh + h]))
                : 0.f;
            const float* w0r = W0 + h * Cc + c0;
            const float* wsr = Wst + h * Cc + c0;
            const float* wdr = Wdt + h * Cc + c0;
            #pragma unroll
            for (int j = 0; j < 32; ++j)
                a += row[j] * w0r[j] + accs[j] * wsr[j] + accd[j] * wdr[j];
            a += __shfl_xor(a, 32);    // combine c-halves
            o[k] = a;
        }
        if ((hb >> 3) == half)
            *(float4*)(Fp + hb * 4) = make_float4(o[0], o[1], o[2], o[3]);
    }
}

// ---------------------------------------------------------------------------
// K4: multi-scale grouped conv over t + GN statistics
__global__ void k4_conv(const float* __restrict__ F,
                        const float* __restrict__ w3, const float* __restrict__ w5,
                        const float* __restrict__ w7, const float* __restrict__ w9,
                        const float* __restrict__ cb,
                        float* __restrict__ xc, float* __restrict__ stats) {
    __shared__ float fl[2 * Tt * Hh];   // [t][nl][h] = 1536
    __shared__ float sstat[64];
    int blk = blockIdx.x;               // B * N/2 = 4096
    int b = blk >> 8; int n0 = (blk & 255) * 2;
    int tid = threadIdx.x;
    if (tid < 64) sstat[tid] = 0.f;
    for (int i = tid; i < 1536; i += 256) {
        int t = i >> 7; int r = i & 127;
        fl[i] = F[(size_t)(b * Tt + t) * Nn * Hh + n0 * Hh + r];
    }
    __syncthreads();
    int nl = tid >> 7; int co = tid & 127;
    int g = co >> 5;
    float a3[10], a5[8], a7[6], a9[4];
    {
        float c3 = cb[co], c5 = cb[128 + co], c7 = cb[256 + co], c9 = cb[384 + co];
        #pragma unroll
        for (int j = 0; j < 10; ++j) a3[j] = c3;
        #pragma unroll
        for (int j = 0; j < 8; ++j) a5[j] = c5;
        #pragma unroll
        for (int j = 0; j < 6; ++j) a7[j] = c7;
        #pragma unroll
        for (int j = 0; j < 4; ++j) a9[j] = c9;
    }
    for (int ci = 0; ci < 16; ++ci) {
        int cig = g * 16 + ci;
        float xr[12];
        #pragma unroll
        for (int tt = 0; tt < 12; ++tt) xr[tt] = fl[tt * 128 + nl * 64 + cig];
        const float* p3 = w3 + (co * 16 + ci) * 3;
        #pragma unroll
        for (int dt = 0; dt < 3; ++dt) {
            float wv = p3[dt];
            #pragma unroll
            for (int j = 0; j < 10; ++j) a3[j] += xr[j + dt] * wv;
        }
        const float* p5 = w5 + (co * 16 + ci) * 5;
        #pragma unroll
        for (int dt = 0; dt < 5; ++dt) {
            float wv = p5[dt];
            #pragma unroll
            for (int j = 0; j < 8; ++j) a5[j] += xr[j + dt] * wv;
        }
        const float* p7 = w7 + (co * 16 + ci) * 7;
        #pragma unroll
        for (int dt = 0; dt < 7; ++dt) {
            float wv = p7[dt];
            #pragma unroll
            for (int j = 0; j < 6; ++j) a7[j] += xr[j + dt] * wv;
        }
        const float* p9 = w9 + (co * 16 + ci) * 9;
        #pragma unroll
        for (int dt = 0; dt < 9; ++dt) {
            float wv = p9[dt];
            #pragma unroll
            for (int j = 0; j < 4; ++j) a9[j] += xr[j + dt] * wv;
        }
    }
    int pg = (co < 64) ? (co >> 4) : 4 + ((co - 64) >> 4);
    float* xcw = xc + ((size_t)(b * Nn + n0 + nl) * 128 + co) * 28;
    float su, sq;
    // scale 0 (k=3)
    su = 0.f; sq = 0.f;
    #pragma unroll
    for (int j = 0; j < 10; ++j) { float v = a3[j]; xcw[j] = v; su += v; sq += v * v; }
    #pragma unroll
    for (int off = 1; off < 16; off <<= 1) { su += __shfl_xor(su, off); sq += __shfl_xor(sq, off); }
    if ((tid & 15) == 0) { atomicAdd(&sstat[(0 * 8 + pg) * 2], su); atomicAdd(&sstat[(0 * 8 + pg) * 2 + 1], sq); }
    // scale 1 (k=5)
    su = 0.f; sq = 0.f;
    #pragma unroll
    for (int j = 0; j < 8; ++j) { float v = a5[j]; xcw[10 + j] = v; su += v; sq += v * v; }
    #pragma unroll
    for (int off = 1; off < 16; off <<= 1) { su += __shfl_xor(su, off); sq += __shfl_xor(sq, off); }
    if ((tid & 15) == 0) { atomicAdd(&sstat[(1 * 8 + pg) * 2], su); atomicAdd(&sstat[(1 * 8 + pg) * 2 + 1], sq); }
    // scale 2 (k=7)
    su = 0.f; sq = 0.f;
    #pragma unroll
    for (int j = 0; j < 6; ++j) { float v = a7[j]; xcw[18 + j] = v; su += v; sq += v * v; }
    #pragma unroll
    for (int off = 1; off < 16; off <<= 1) { su += __shfl_xor(su, off); sq += __shfl_xor(sq, off); }
    if ((tid & 15) == 0) { atomicAdd(&sstat[(2 * 8 + pg) * 2], su); atomicAdd(&sstat[(2 * 8 + pg) * 2 + 1], sq); }
    // scale 3 (k=9)
    su = 0.f; sq = 0.f;
    #pragma unroll
    for (int j = 0; j < 4; ++j) { float v = a9[j]; xcw[24 + j] = v; su += v; sq += v * v; }
    #pragma unroll
    for (int off = 1; off < 16; off <<= 1) { su += __shfl_xor(su, off); sq += __shfl_xor(sq, off); }
    if ((tid & 15) == 0) { atomicAdd(&sstat[(3 * 8 + pg) * 2], su); atomicAdd(&sstat[(3 * 8 + pg) * 2 + 1], sq); }
    __syncthreads();
    if (tid < 64) {
        int s = tid >> 4; int pgq = (tid >> 1) & 7; int st = tid & 1;
        atomicAdd(&stats[((s * Bb + b) * 8 + pgq) * 2 + st], sstat[(s * 8 + pgq) * 2 + st]);
    }
}

// ---------------------------------------------------------------------------
// K5: GN + Mish*Hardtanh + fc + residual + LN -> out[b][n][h][t]
__global__ __launch_bounds__(256) void k5_final(
                         const float* __restrict__ xc, const float* __restrict__ stats,
                         const float* __restrict__ x,
                         const float* __restrict__ gpw, const float* __restrict__ gpb,
                         const float* __restrict__ gqw, const float* __restrict__ gqb,
                         const float* __restrict__ fcw, const float* __restrict__ fcb,
                         const float* __restrict__ resT, const float* __restrict__ rb,
                         const float* __restrict__ lnw, const float* __restrict__ lnb,
                         float* __restrict__ out) {
    int blk = blockIdx.x;               // 2048 = B * N/4
    int b = blk >> 7; int n = (blk & 127) * 4 + (threadIdx.x >> 6);
    int h = threadIdx.x & 63;
    int pg = h >> 4;
    const int TkA[4] = {10, 8, 6, 4};
    float mu_p[4], rs_p[4], mu_q[4], rs_q[4];
    #pragma unroll
    for (int s = 0; s < 4; ++s) {
        float cnt = 16.f * 512.f * (float)TkA[s];
        float su = stats[((s * Bb + b) * 8 + pg) * 2];
        float sq = stats[((s * Bb + b) * 8 + pg) * 2 + 1];
        float mu = su / cnt; float var = sq / cnt - mu * mu;
        mu_p[s] = mu; rs_p[s] = rsqrtf(var + 1e-5f);
        su = stats[((s * Bb + b) * 8 + 4 + pg) * 2];
        sq = stats[((s * Bb + b) * 8 + 4 + pg) * 2 + 1];
        mu = su / cnt; var = sq / cnt - mu * mu;
        mu_q[s] = mu; rs_q[s] = rsqrtf(var + 1e-5f);
    }
    const float* xcp = xc + ((size_t)(b * Nn + n) * 128 + h) * 28;
    const float* xcq = xcp + 64 * 28;
    float pb_[28], qb_[28];
    {
        const float4* p4 = (const float4*)xcp;
        const float4* q4 = (const float4*)xcq;
        #pragma unroll
        for (int j = 0; j < 7; ++j) {
            float4 a = p4[j];
            pb_[j*4] = a.x; pb_[j*4+1] = a.y; pb_[j*4+2] = a.z; pb_[j*4+3] = a.w;
            float4 c = q4[j];
            qb_[j*4] = c.x; qb_[j*4+1] = c.y; qb_[j*4+2] = c.z; qb_[j*4+3] = c.w;
        }
    }
    float tc[28];
    int off = 0;
    #pragma unroll
    for (int s = 0; s < 4; ++s) {
        float pw = gpw[s * 64 + h], pbv = gpb[s * 64 + h];
        float qw = gqw[s * 64 + h], qbv = gqb[s * 64 + h];
        #pragma unroll
        for (int j = 0; j < 10; ++j) {
            if (j < TkA[s]) {
                float p = (pb_[off + j] - mu_p[s]) * rs_p[s] * pw + pbv;
                float q = (qb_[off + j] - mu_q[s]) * rs_q[s] * qw + qbv;
                // mish(p) = p * tanh(softplus(p)); tanh(sp) = (z^2-1)/(z^2+1), z = 1+e^p
                float mish;
                if (p > 20.f) mish = p;
                else { float z = 1.f + __expf(p); float z2 = z * z; mish = p * (z2 - 1.f) / (z2 + 1.f); }
                float gate = fminf(fmaxf(q, 0.f), 1.f);
                tc[off + j] = mish * gate;
            }
        }
        off += TkA[s];
    }
    float o[12];
    #pragma unroll
    for (int t = 0; t < 12; ++t) {
        float a = fcb[t];
        #pragma unroll
        for (int k = 0; k < 28; ++k) a += tc[k] * fcw[t * 28 + k];
        o[t] = fmaxf(a, 0.f);
    }
    const float* xr = x + (size_t)(b * Nn + n) * CT;
    float res[12];
    float rbv = rb[h];
    #pragma unroll
    for (int t = 0; t < 12; ++t) res[t] = rbv;
    for (int c = 0; c < 64; ++c) {
        float rv = resT[c * 64 + h];
        #pragma unroll
        for (int t = 0; t < 12; ++t) res[t] += xr[c * 12 + t] * rv;
    }
    float y[12];
    #pragma unroll
    for (int t = 0; t < 12; ++t) y[t] = fmaxf(res[t] + o[t], 0.f);
    float lw = lnw[h], lb = lnb[h];
    float* op = out + ((size_t)(b * Nn + n) * Hh + h) * Tt;
    #pragma unroll
    for (int t = 0; t < 12; ++t) {
        float s1 = y[t], s2 = y[t] * y[t];
        #pragma unroll
        for (int o2 = 32; o2 > 0; o2 >>= 1) {
            s1 += __shfl_xor(s1, o2);
            s2 += __shfl_xor(s2, o2);
        }
        float mu = s1 * (1.f / 64.f);
        float var = s2 * (1.f / 64.f) - mu * mu;
        op[t] = (y[t] - mu) * rsqrtf(var + 1e-5f) * lw + lb;
    }
}

// ---------------------------------------------------------------------------
extern "C" void kernel_launch(void* const* d_in, const int* in_sizes, int n_in,
                              void* d_out, int out_size, void* d_ws, size_t ws_size,
                              hipStream_t stream) {
    const float* x    = (const float*)d_in[0];
    const float* adj  = (const float*)d_in[1];
    const float* U1   = (const float*)d_in[2];
    const float* U2   = (const float*)d_in[3];
    const float* U3   = (const float*)d_in[4];
    const float* be   = (const float*)d_in[5];
    const float* Ve   = (const float*)d_in[6];
    const float* W0   = (const float*)d_in[7];
    const float* b0   = (const float*)d_in[8];
    const float* masks= (const float*)d_in[9];
    const float* Ws   = (const float*)d_in[10];
    const float* bs   = (const float*)d_in[11];
    const float* Wd   = (const float*)d_in[12];
    const float* bd   = (const float*)d_in[13];
    const float* w3   = (const float*)d_in[14];
    const float* w5   = (const float*)d_in[15];
    const float* w7   = (const float*)d_in[16];
    const float* w9   = (const float*)d_in[17];
    const float* cb   = (const float*)d_in[18];
    const float* gpw  = (const float*)d_in[19];
    const float* gpb  = (const float*)d_in[20];
    const float* gqw  = (const float*)d_in[21];
    const float* gqb  = (const float*)d_in[22];
    const float* fcw  = (const float*)d_in[23];
    const float* fcb  = (const float*)d_in[24];
    const float* rw   = (const float*)d_in[25];
    const float* rb   = (const float*)d_in[26];
    const float* lnw  = (const float*)d_in[27];
    const float* lnb  = (const float*)d_in[28];
    float* out = (float*)d_out;
    float* ws  = (float*)d_ws;

    float* tmp1  = ws;                  // 12288
    float* stats = ws + 12288;          // 1024
    float* At    = ws + 13312;          // 2304
    float* rhs   = ws + 15616;          // 98304
    float* resT  = ws + 113920;         // 4096
    float* xtT   = ws + 118016;         // 6291456
    float* enhT  = ws + 6409472;        // 3145728
    float* F     = ws + 9555200;        // 6291456
    float* xc    = ws + 15846656;       // 29360128  (end: 45206784 floats = 181 MB)

    hipMemsetAsync(ws, 0, 13312 * sizeof(float), stream);  // tmp1 + stats

    k0_rest<<<16, 256, 0, stream>>>(rw, resT);
    k1a_tmp1<<<192, 256, 0, stream>>>(x, U1, tmp1);
    k1b_rhs<<<384, 256, 0, stream>>>(x, U3, rhs);
    k2b_enh<<<3072, 256, 0, stream>>>(adj, masks, enhT);
    k1c_att<<<16, 256, 0, stream>>>(tmp1, rhs, U2, be, Ve, At);
    k2_xtt<<<2048, 256, 0, stream>>>(x, At, xtT);
    k3_gcn<<<768, 256, 0, stream>>>(xtT, enhT, W0, b0, Ws, bs, Wd, bd, F);
    k4_conv<<<4096, 256, 0, stream>>>(F, w3, w5, w7, w9, cb, xc, stats);
    k5_final<<<2048, 256, 0, stream>>>(xc, stats, x, gpw, gpb, gqw, gqb,
                                       fcw, fcb, resT, rb, lnw, lnb, out);
}